// Round 1
// 443.247 us; speedup vs baseline: 1.0043x; 1.0043x over previous
//
#include <hip/hip_runtime.h>
#include <math.h>

// Weighted Procrustes (Kabsch), two-phase:
//  Phase 1: per-batch streaming reduction. ONE BLOCK (4 waves / 256 thr)
//           per batch; each wave streams a contiguous quarter (14 KB,
//           2 fully-unrolled float4 iterations per stream -> 14 loads in
//           flight at wave start). Grid = 8192 blocks = 32768 waves = 4x
//           machine oversubscription so the scheduler backfills stragglers
//           (previous 1-wave-per-batch version was exactly-resident: avg
//           occupancy 37%, kernel time == slowest wave, no backfill).
//           Per-wave 96-shuffle butterfly, then 256 B LDS combine.
//  Phase 2: 8192 independent Horn-quaternion solves, one per thread.

constexpr int kB = 8192;
constexpr int kN = 2048;
constexpr float kEps = 1e-5f;
constexpr int kWavesPerBatch = 4;                       // 256 threads/block
constexpr int kIters = kN / 4 / 64 / kWavesPerBatch;    // 2 float4-iters/wave

__global__ __launch_bounds__(256) void wproc_reduce(
    const float* __restrict__ src,
    const float* __restrict__ src_corr,
    const float* __restrict__ weights,
    float* __restrict__ ws)
{
    const int lane = threadIdx.x & 63;
    const int wave = threadIdx.x >> 6;
    const int b = blockIdx.x;

    const float* arow = src + (size_t)b * 3 * kN;
    const float* brow = src_corr + (size_t)b * 3 * kN;
    const float4* w4  = reinterpret_cast<const float4*>(weights + (size_t)b * kN);
    const float4* ax4 = reinterpret_cast<const float4*>(arow);
    const float4* ay4 = reinterpret_cast<const float4*>(arow + kN);
    const float4* az4 = reinterpret_cast<const float4*>(arow + 2 * kN);
    const float4* bx4 = reinterpret_cast<const float4*>(brow);
    const float4* by4 = reinterpret_cast<const float4*>(brow + kN);
    const float4* bz4 = reinterpret_cast<const float4*>(brow + 2 * kN);

    // acc: [0]=Σw [1..3]=Σw*a [4..6]=Σw*b [7..15]=Σw*a_d*b_e
    float acc[16];
#pragma unroll
    for (int i = 0; i < 16; ++i) acc[i] = 0.f;

#pragma unroll
    for (int it = 0; it < kIters; ++it) {
        const int idx = (wave * kIters + it) * 64 + lane;
        const float4 w  = w4[idx];
        const float4 ax = ax4[idx];
        const float4 ay = ay4[idx];
        const float4 az = az4[idx];
        const float4 bx = bx4[idx];
        const float4 by = by4[idx];
        const float4 bz = bz4[idx];
        const float wc[4]  = {w.x,  w.y,  w.z,  w.w};
        const float axc[4] = {ax.x, ax.y, ax.z, ax.w};
        const float ayc[4] = {ay.x, ay.y, ay.z, ay.w};
        const float azc[4] = {az.x, az.y, az.z, az.w};
        const float bxc[4] = {bx.x, bx.y, bx.z, bx.w};
        const float byc[4] = {by.x, by.y, by.z, by.w};
        const float bzc[4] = {bz.x, bz.y, bz.z, bz.w};
#pragma unroll
        for (int c = 0; c < 4; ++c) {
            const float ww  = wc[c];
            const float wax = ww * axc[c], way = ww * ayc[c], waz = ww * azc[c];
            const float bxx = bxc[c], byy = byc[c], bzz = bzc[c];
            acc[0]  += ww;
            acc[1]  += wax;                acc[2]  += way;                acc[3]  += waz;
            acc[4]  = fmaf(ww,  bxx, acc[4]);  acc[5]  = fmaf(ww,  byy, acc[5]);  acc[6]  = fmaf(ww,  bzz, acc[6]);
            acc[7]  = fmaf(wax, bxx, acc[7]);  acc[8]  = fmaf(wax, byy, acc[8]);  acc[9]  = fmaf(wax, bzz, acc[9]);
            acc[10] = fmaf(way, bxx, acc[10]); acc[11] = fmaf(way, byy, acc[11]); acc[12] = fmaf(way, bzz, acc[12]);
            acc[13] = fmaf(waz, bxx, acc[13]); acc[14] = fmaf(waz, byy, acc[14]); acc[15] = fmaf(waz, bzz, acc[15]);
        }
    }

    // per-wave 64-lane butterfly (amortized over 14 KB of data)
#pragma unroll
    for (int i = 0; i < 16; ++i) {
        float v = acc[i];
#pragma unroll
        for (int off = 32; off > 0; off >>= 1)
            v += __shfl_down(v, off, 64);
        acc[i] = v;
    }

    // cross-wave combine: 256 B LDS + one barrier
    __shared__ float part[kWavesPerBatch][16];
    if (lane == 0) {
#pragma unroll
        for (int i = 0; i < 16; ++i) part[wave][i] = acc[i];
    }
    __syncthreads();
    if (threadIdx.x < 16) {
        const int t = threadIdx.x;
        float s = part[0][t] + part[1][t] + part[2][t] + part[3][t];
        ws[(size_t)b * 16 + t] = s;
    }
}

__global__ __launch_bounds__(256) void wproc_solve(
    const float* __restrict__ ws,
    float* __restrict__ out)
{
    const int b = blockIdx.x * blockDim.x + threadIdx.x;
    if (b >= kB) return;

    float t[16];
#pragma unroll
    for (int i = 0; i < 4; ++i) {
        const float4 v = reinterpret_cast<const float4*>(ws + (size_t)b * 16)[i];
        t[4 * i] = v.x; t[4 * i + 1] = v.y; t[4 * i + 2] = v.z; t[4 * i + 3] = v.w;
    }

    const float W   = t[0];
    const float inv = 1.f / (W + kEps);
    const float S   = W * inv;
    float ca[3], cb[3];
#pragma unroll
    for (int d = 0; d < 3; ++d) { ca[d] = t[1 + d] * inv; cb[d] = t[4 + d] * inv; }

    float M[3][3];
    const float f2 = 2.f - S;
#pragma unroll
    for (int d = 0; d < 3; ++d)
#pragma unroll
        for (int e = 0; e < 3; ++e)
            M[d][e] = t[7 + 3 * d + e] * inv - ca[d] * cb[e] * f2;

    const float T  = M[0][0] + M[1][1] + M[2][2];
    const float cx = M[1][2] - M[2][1];
    const float cy = M[2][0] - M[0][2];
    const float cz = M[0][1] - M[1][0];
    float Nm[4][4];
    Nm[0][0] = T;
    Nm[0][1] = Nm[1][0] = cx;
    Nm[0][2] = Nm[2][0] = cy;
    Nm[0][3] = Nm[3][0] = cz;
    Nm[1][1] = 2.f * M[0][0] - T;
    Nm[2][2] = 2.f * M[1][1] - T;
    Nm[3][3] = 2.f * M[2][2] - T;
    Nm[1][2] = Nm[2][1] = M[0][1] + M[1][0];
    Nm[1][3] = Nm[3][1] = M[0][2] + M[2][0];
    Nm[2][3] = Nm[3][2] = M[1][2] + M[2][1];

    float Vv[4][4] = {{1,0,0,0},{0,1,0,0},{0,0,1,0},{0,0,0,1}};
    const int pp[6] = {0,0,0,1,1,2};
    const int qq[6] = {1,2,3,2,3,3};
    for (int sweep = 0; sweep < 6; ++sweep) {
        for (int r = 0; r < 6; ++r) {
            const int p = pp[r], q = qq[r];
            const float apq = Nm[p][q];
            if (fabsf(apq) < 1e-12f) continue;
            const float tau = (Nm[q][q] - Nm[p][p]) / (2.f * apq);
            const float tt  = copysignf(1.f, tau) / (fabsf(tau) + sqrtf(1.f + tau * tau));
            const float c   = 1.f / sqrtf(1.f + tt * tt);
            const float s   = tt * c;
            const float app = Nm[p][p], aqq = Nm[q][q];
            Nm[p][p] = app - tt * apq;
            Nm[q][q] = aqq + tt * apq;
            Nm[p][q] = Nm[q][p] = 0.f;
#pragma unroll
            for (int k = 0; k < 4; ++k) {
                if (k == p || k == q) continue;
                const float akp = Nm[k][p], akq = Nm[k][q];
                Nm[k][p] = Nm[p][k] = c * akp - s * akq;
                Nm[k][q] = Nm[q][k] = s * akp + c * akq;
            }
#pragma unroll
            for (int k = 0; k < 4; ++k) {
                const float vkp = Vv[k][p], vkq = Vv[k][q];
                Vv[k][p] = c * vkp - s * vkq;
                Vv[k][q] = s * vkp + c * vkq;
            }
        }
    }

    int jm = 0;
#pragma unroll
    for (int j = 1; j < 4; ++j) if (Nm[j][j] > Nm[jm][jm]) jm = j;
    float qw = Vv[0][jm], qx = Vv[1][jm], qy = Vv[2][jm], qz = Vv[3][jm];
    const float nq = 1.f / sqrtf(qw * qw + qx * qx + qy * qy + qz * qz);
    qw *= nq; qx *= nq; qy *= nq; qz *= nq;

    float R[3][3];
    R[0][0] = 1.f - 2.f * (qy * qy + qz * qz);
    R[0][1] = 2.f * (qx * qy - qw * qz);
    R[0][2] = 2.f * (qx * qz + qw * qy);
    R[1][0] = 2.f * (qx * qy + qw * qz);
    R[1][1] = 1.f - 2.f * (qx * qx + qz * qz);
    R[1][2] = 2.f * (qy * qz - qw * qx);
    R[2][0] = 2.f * (qx * qz - qw * qy);
    R[2][1] = 2.f * (qy * qz + qw * qx);
    R[2][2] = 1.f - 2.f * (qx * qx + qy * qy);

    float* ro = out + (size_t)b * 9;
#pragma unroll
    for (int i = 0; i < 3; ++i)
#pragma unroll
        for (int j = 0; j < 3; ++j)
            ro[3 * i + j] = R[i][j];

    float* to = out + (size_t)kB * 9 + (size_t)b * 3;
#pragma unroll
    for (int i = 0; i < 3; ++i)
        to[i] = cb[i] - (R[i][0] * ca[0] + R[i][1] * ca[1] + R[i][2] * ca[2]);
}

extern "C" void kernel_launch(void* const* d_in, const int* in_sizes, int n_in,
                              void* d_out, int out_size, void* d_ws, size_t ws_size,
                              hipStream_t stream) {
    const float* src      = (const float*)d_in[0];
    const float* src_corr = (const float*)d_in[1];
    const float* weights  = (const float*)d_in[2];
    float* out = (float*)d_out;
    float* ws  = (float*)d_ws;   // 8192*16 floats = 512 KB
    wproc_reduce<<<kB, 64 * kWavesPerBatch, 0, stream>>>(src, src_corr, weights, ws);
    wproc_solve<<<(kB + 255) / 256, 256, 0, stream>>>(ws, out);
}

// Round 2
// 433.952 us; speedup vs baseline: 1.0258x; 1.0214x over previous
//
#include <hip/hip_runtime.h>
#include <math.h>

// Weighted Procrustes (Kabsch), two-phase:
//  Phase 1: per-batch streaming reduction. ONE BLOCK (4 waves / 256 thr)
//           per batch; each wave streams a contiguous quarter (14 KB).
//           All 14 float4 loads are issued before any FMA (explicit
//           register staging -> 14 outstanding loads/wave for latency
//           hiding). Per-wave 96-shuffle butterfly, 256 B LDS combine.
//  Phase 2: 8192 independent Horn-quaternion solves, one per thread.
//           Jacobi rotations are template<P,Q>-instantiated so EVERY
//           index into Nm/Vv is compile-time: the previous version's
//           runtime pp[r]/qq[r] and Vv[*][jm] indexing forced both
//           4x4 arrays into scratch memory (rule: one runtime index
//           poisons the whole alloca) -> ~36 serial scratch round-trips.

constexpr int kB = 8192;
constexpr int kN = 2048;
constexpr float kEps = 1e-5f;
constexpr int kWavesPerBatch = 4;                       // 256 threads/block
constexpr int kIters = kN / 4 / 64 / kWavesPerBatch;    // 2 float4-iters/wave

__global__ __launch_bounds__(256) void wproc_reduce(
    const float* __restrict__ src,
    const float* __restrict__ src_corr,
    const float* __restrict__ weights,
    float* __restrict__ ws)
{
    const int lane = threadIdx.x & 63;
    const int wave = threadIdx.x >> 6;
    const int b = blockIdx.x;

    const float* arow = src + (size_t)b * 3 * kN;
    const float* brow = src_corr + (size_t)b * 3 * kN;
    const float4* w4  = reinterpret_cast<const float4*>(weights + (size_t)b * kN);
    const float4* ax4 = reinterpret_cast<const float4*>(arow);
    const float4* ay4 = reinterpret_cast<const float4*>(arow + kN);
    const float4* az4 = reinterpret_cast<const float4*>(arow + 2 * kN);
    const float4* bx4 = reinterpret_cast<const float4*>(brow);
    const float4* by4 = reinterpret_cast<const float4*>(brow + kN);
    const float4* bz4 = reinterpret_cast<const float4*>(brow + 2 * kN);

    // Stage ALL loads first (static indices -> registers; 14 loads in flight)
    float4 Lw[kIters], Lax[kIters], Lay[kIters], Laz[kIters];
    float4 Lbx[kIters], Lby[kIters], Lbz[kIters];
#pragma unroll
    for (int it = 0; it < kIters; ++it) {
        const int idx = (wave * kIters + it) * 64 + lane;
        Lw[it]  = w4[idx];
        Lax[it] = ax4[idx];
        Lay[it] = ay4[idx];
        Laz[it] = az4[idx];
        Lbx[it] = bx4[idx];
        Lby[it] = by4[idx];
        Lbz[it] = bz4[idx];
    }

    // acc: [0]=Σw [1..3]=Σw*a [4..6]=Σw*b [7..15]=Σw*a_d*b_e
    float acc[16];
#pragma unroll
    for (int i = 0; i < 16; ++i) acc[i] = 0.f;

#pragma unroll
    for (int it = 0; it < kIters; ++it) {
        const float wc[4]  = {Lw[it].x,  Lw[it].y,  Lw[it].z,  Lw[it].w};
        const float axc[4] = {Lax[it].x, Lax[it].y, Lax[it].z, Lax[it].w};
        const float ayc[4] = {Lay[it].x, Lay[it].y, Lay[it].z, Lay[it].w};
        const float azc[4] = {Laz[it].x, Laz[it].y, Laz[it].z, Laz[it].w};
        const float bxc[4] = {Lbx[it].x, Lbx[it].y, Lbx[it].z, Lbx[it].w};
        const float byc[4] = {Lby[it].x, Lby[it].y, Lby[it].z, Lby[it].w};
        const float bzc[4] = {Lbz[it].x, Lbz[it].y, Lbz[it].z, Lbz[it].w};
#pragma unroll
        for (int c = 0; c < 4; ++c) {
            const float ww  = wc[c];
            const float wax = ww * axc[c], way = ww * ayc[c], waz = ww * azc[c];
            const float bxx = bxc[c], byy = byc[c], bzz = bzc[c];
            acc[0]  += ww;
            acc[1]  += wax;                acc[2]  += way;                acc[3]  += waz;
            acc[4]  = fmaf(ww,  bxx, acc[4]);  acc[5]  = fmaf(ww,  byy, acc[5]);  acc[6]  = fmaf(ww,  bzz, acc[6]);
            acc[7]  = fmaf(wax, bxx, acc[7]);  acc[8]  = fmaf(wax, byy, acc[8]);  acc[9]  = fmaf(wax, bzz, acc[9]);
            acc[10] = fmaf(way, bxx, acc[10]); acc[11] = fmaf(way, byy, acc[11]); acc[12] = fmaf(way, bzz, acc[12]);
            acc[13] = fmaf(waz, bxx, acc[13]); acc[14] = fmaf(waz, byy, acc[14]); acc[15] = fmaf(waz, bzz, acc[15]);
        }
    }

    // per-wave 64-lane butterfly
#pragma unroll
    for (int i = 0; i < 16; ++i) {
        float v = acc[i];
#pragma unroll
        for (int off = 32; off > 0; off >>= 1)
            v += __shfl_down(v, off, 64);
        acc[i] = v;
    }

    // cross-wave combine: 256 B LDS + one barrier
    __shared__ float part[kWavesPerBatch][16];
    if (lane == 0) {
#pragma unroll
        for (int i = 0; i < 16; ++i) part[wave][i] = acc[i];
    }
    __syncthreads();
    if (threadIdx.x < 16) {
        const int t = threadIdx.x;
        float s = part[0][t] + part[1][t] + part[2][t] + part[3][t];
        ws[(size_t)b * 16 + t] = s;
    }
}

// Jacobi rotation with COMPILE-TIME indices: after inlining, every access
// to Nm/Vv is a constant index -> SROA keeps both 4x4 arrays in VGPRs.
template<int P, int Q>
__device__ __forceinline__ void jrot(float (&Nm)[4][4], float (&Vv)[4][4]) {
    const float apq = Nm[P][Q];
    if (fabsf(apq) >= 1e-12f) {
        const float tau = (Nm[Q][Q] - Nm[P][P]) / (2.f * apq);
        const float tt  = copysignf(1.f, tau) / (fabsf(tau) + sqrtf(1.f + tau * tau));
        const float c   = 1.f / sqrtf(1.f + tt * tt);
        const float s   = tt * c;
        const float app = Nm[P][P], aqq = Nm[Q][Q];
        Nm[P][P] = app - tt * apq;
        Nm[Q][Q] = aqq + tt * apq;
        Nm[P][Q] = Nm[Q][P] = 0.f;
#pragma unroll
        for (int k = 0; k < 4; ++k) {
            if (k == P || k == Q) continue;
            const float akp = Nm[k][P], akq = Nm[k][Q];
            Nm[k][P] = Nm[P][k] = c * akp - s * akq;
            Nm[k][Q] = Nm[Q][k] = s * akp + c * akq;
        }
#pragma unroll
        for (int k = 0; k < 4; ++k) {
            const float vkp = Vv[k][P], vkq = Vv[k][Q];
            Vv[k][P] = c * vkp - s * vkq;
            Vv[k][Q] = s * vkp + c * vkq;
        }
    }
}

__global__ __launch_bounds__(64) void wproc_solve(
    const float* __restrict__ ws,
    float* __restrict__ out)
{
    const int b = blockIdx.x * blockDim.x + threadIdx.x;
    if (b >= kB) return;

    float t[16];
#pragma unroll
    for (int i = 0; i < 4; ++i) {
        const float4 v = reinterpret_cast<const float4*>(ws + (size_t)b * 16)[i];
        t[4 * i] = v.x; t[4 * i + 1] = v.y; t[4 * i + 2] = v.z; t[4 * i + 3] = v.w;
    }

    const float W   = t[0];
    const float inv = 1.f / (W + kEps);
    const float S   = W * inv;
    float ca[3], cb[3];
#pragma unroll
    for (int d = 0; d < 3; ++d) { ca[d] = t[1 + d] * inv; cb[d] = t[4 + d] * inv; }

    float M[3][3];
    const float f2 = 2.f - S;
#pragma unroll
    for (int d = 0; d < 3; ++d)
#pragma unroll
        for (int e = 0; e < 3; ++e)
            M[d][e] = t[7 + 3 * d + e] * inv - ca[d] * cb[e] * f2;

    const float T  = M[0][0] + M[1][1] + M[2][2];
    const float cx = M[1][2] - M[2][1];
    const float cy = M[2][0] - M[0][2];
    const float cz = M[0][1] - M[1][0];
    float Nm[4][4];
    Nm[0][0] = T;
    Nm[0][1] = Nm[1][0] = cx;
    Nm[0][2] = Nm[2][0] = cy;
    Nm[0][3] = Nm[3][0] = cz;
    Nm[1][1] = 2.f * M[0][0] - T;
    Nm[2][2] = 2.f * M[1][1] - T;
    Nm[3][3] = 2.f * M[2][2] - T;
    Nm[1][2] = Nm[2][1] = M[0][1] + M[1][0];
    Nm[1][3] = Nm[3][1] = M[0][2] + M[2][0];
    Nm[2][3] = Nm[3][2] = M[1][2] + M[2][1];

    float Vv[4][4] = {{1,0,0,0},{0,1,0,0},{0,0,1,0},{0,0,0,1}};

    // 6 sweeps, rotation order (0,1)(0,2)(0,3)(1,2)(1,3)(2,3),
    // all indices compile-time.
    for (int sweep = 0; sweep < 6; ++sweep) {
        jrot<0, 1>(Nm, Vv);
        jrot<0, 2>(Nm, Vv);
        jrot<0, 3>(Nm, Vv);
        jrot<1, 2>(Nm, Vv);
        jrot<1, 3>(Nm, Vv);
        jrot<2, 3>(Nm, Vv);
    }

    // Branchless largest-eigenvalue column select (static indices only).
    float best = Nm[0][0];
    float qw = Vv[0][0], qx = Vv[1][0], qy = Vv[2][0], qz = Vv[3][0];
    if (Nm[1][1] > best) { best = Nm[1][1]; qw = Vv[0][1]; qx = Vv[1][1]; qy = Vv[2][1]; qz = Vv[3][1]; }
    if (Nm[2][2] > best) { best = Nm[2][2]; qw = Vv[0][2]; qx = Vv[1][2]; qy = Vv[2][2]; qz = Vv[3][2]; }
    if (Nm[3][3] > best) { best = Nm[3][3]; qw = Vv[0][3]; qx = Vv[1][3]; qy = Vv[2][3]; qz = Vv[3][3]; }

    const float nq = 1.f / sqrtf(qw * qw + qx * qx + qy * qy + qz * qz);
    qw *= nq; qx *= nq; qy *= nq; qz *= nq;

    float R[3][3];
    R[0][0] = 1.f - 2.f * (qy * qy + qz * qz);
    R[0][1] = 2.f * (qx * qy - qw * qz);
    R[0][2] = 2.f * (qx * qz + qw * qy);
    R[1][0] = 2.f * (qx * qy + qw * qz);
    R[1][1] = 1.f - 2.f * (qx * qx + qz * qz);
    R[1][2] = 2.f * (qy * qz - qw * qx);
    R[2][0] = 2.f * (qx * qz - qw * qy);
    R[2][1] = 2.f * (qy * qz + qw * qx);
    R[2][2] = 1.f - 2.f * (qx * qx + qy * qy);

    float* ro = out + (size_t)b * 9;
#pragma unroll
    for (int i = 0; i < 3; ++i)
#pragma unroll
        for (int j = 0; j < 3; ++j)
            ro[3 * i + j] = R[i][j];

    float* to = out + (size_t)kB * 9 + (size_t)b * 3;
#pragma unroll
    for (int i = 0; i < 3; ++i)
        to[i] = cb[i] - (R[i][0] * ca[0] + R[i][1] * ca[1] + R[i][2] * ca[2]);
}

extern "C" void kernel_launch(void* const* d_in, const int* in_sizes, int n_in,
                              void* d_out, int out_size, void* d_ws, size_t ws_size,
                              hipStream_t stream) {
    const float* src      = (const float*)d_in[0];
    const float* src_corr = (const float*)d_in[1];
    const float* weights  = (const float*)d_in[2];
    float* out = (float*)d_out;
    float* ws  = (float*)d_ws;   // 8192*16 floats = 512 KB
    wproc_reduce<<<kB, 64 * kWavesPerBatch, 0, stream>>>(src, src_corr, weights, ws);
    // 64-thread blocks: 128 blocks spread the 8192 independent serial
    // solves across 128 CUs (1 wave each) instead of 32 CUs.
    wproc_solve<<<kB / 64, 64, 0, stream>>>(ws, out);
}

// Round 3
// 430.301 us; speedup vs baseline: 1.0345x; 1.0085x over previous
//
#include <hip/hip_runtime.h>
#include <math.h>
#include <stdint.h>

// Weighted Procrustes (Kabsch), two-phase:
//  Phase 1: per-batch streaming reduction, ONE BLOCK (4 waves) per batch.
//           Data path goes global -> LDS via __builtin_amdgcn_global_load_lds
//           width=16: each wave issues its 14 async 1KB staging instructions
//           with ZERO data VGPRs, so all 14 stay in flight (the previous
//           register-staging version was folded to ~5-in-flight by the
//           compiler: VGPR_Count=40 < the 56 needed -> latency-starved at
//           3.2 TB/s blended). Per-wave s_waitcnt vmcnt(0) (own loads only,
//           no barrier), ds_read_b128 back, FMA, butterfly, LDS combine.
//           LDS 57.6 KB/block -> 2 blocks/CU; in-flight = 112 KB/CU.
//  Phase 2: 8192 independent Horn-quaternion solves, one per thread,
//           fully register-resident (template<P,Q> Jacobi rotations).

constexpr int kB = 8192;
constexpr int kN = 2048;
constexpr float kEps = 1e-5f;
constexpr int kWavesPerBatch = 4;                   // 256 threads/block
constexpr int kFloatsPerWave = kN / kWavesPerBatch; // 512 floats/stream/wave
constexpr int kInstr = kFloatsPerWave / 256;        // 2 x 1KB instr/stream/wave

typedef const __attribute__((address_space(1))) void* gas_ptr;
typedef __attribute__((address_space(3))) void* las_ptr;

// async global->LDS, 16 B/lane. Global addr is PER-LANE; LDS dest is
// wave-uniform base + lane*16 (linear). Layout here is linear -> valid.
__device__ __forceinline__ void async16(const float* g, float* l) {
    __builtin_amdgcn_global_load_lds((gas_ptr)g, (las_ptr)l, 16, 0, 0);
}

__global__ __launch_bounds__(256) void wproc_reduce(
    const float* __restrict__ src,
    const float* __restrict__ src_corr,
    const float* __restrict__ weights,
    float* __restrict__ ws)
{
    const int lane = threadIdx.x & 63;
    const int wave = threadIdx.x >> 6;
    const int b = blockIdx.x;

    __shared__ __align__(16) float lds[7][kN];      // 56 KB staging
    __shared__ float part[kWavesPerBatch][16];      // combine buffer

    const float* g0 = weights  + (size_t)b * kN;        // w
    const float* ga = src      + (size_t)b * 3 * kN;    // ax, ay, az
    const float* gb = src_corr + (size_t)b * 3 * kN;    // bx, by, bz
    const float* base[7] = { g0, ga, ga + kN, ga + 2 * kN,
                                 gb, gb + kN, gb + 2 * kN };

    const int woff = wave * kFloatsPerWave;

    // Stage this wave's quarter of all 7 streams: 14 async loads in flight.
#pragma unroll
    for (int s = 0; s < 7; ++s) {
#pragma unroll
        for (int i = 0; i < kInstr; ++i) {
            const int o = woff + i * 256;
            async16(base[s] + o + lane * 4, &lds[s][o]);
        }
    }

    // Wait for THIS wave's loads (vmcnt is per-wave; we read only our
    // own quarter, so no __syncthreads needed here).
    asm volatile("s_waitcnt vmcnt(0)" ::: "memory");

    // acc: [0]=Σw [1..3]=Σw*a [4..6]=Σw*b [7..15]=Σw*a_d*b_e
    float acc[16];
#pragma unroll
    for (int i = 0; i < 16; ++i) acc[i] = 0.f;

#pragma unroll
    for (int it = 0; it < kInstr; ++it) {
        const int off = woff + it * 256 + lane * 4;  // 16 B/lane, conflict-free
        const float4 w  = *reinterpret_cast<const float4*>(&lds[0][off]);
        const float4 ax = *reinterpret_cast<const float4*>(&lds[1][off]);
        const float4 ay = *reinterpret_cast<const float4*>(&lds[2][off]);
        const float4 az = *reinterpret_cast<const float4*>(&lds[3][off]);
        const float4 bx = *reinterpret_cast<const float4*>(&lds[4][off]);
        const float4 by = *reinterpret_cast<const float4*>(&lds[5][off]);
        const float4 bz = *reinterpret_cast<const float4*>(&lds[6][off]);
        const float wc[4]  = {w.x,  w.y,  w.z,  w.w};
        const float axc[4] = {ax.x, ax.y, ax.z, ax.w};
        const float ayc[4] = {ay.x, ay.y, ay.z, ay.w};
        const float azc[4] = {az.x, az.y, az.z, az.w};
        const float bxc[4] = {bx.x, bx.y, bx.z, bx.w};
        const float byc[4] = {by.x, by.y, by.z, by.w};
        const float bzc[4] = {bz.x, bz.y, bz.z, bz.w};
#pragma unroll
        for (int c = 0; c < 4; ++c) {
            const float ww  = wc[c];
            const float wax = ww * axc[c], way = ww * ayc[c], waz = ww * azc[c];
            const float bxx = bxc[c], byy = byc[c], bzz = bzc[c];
            acc[0]  += ww;
            acc[1]  += wax;                acc[2]  += way;                acc[3]  += waz;
            acc[4]  = fmaf(ww,  bxx, acc[4]);  acc[5]  = fmaf(ww,  byy, acc[5]);  acc[6]  = fmaf(ww,  bzz, acc[6]);
            acc[7]  = fmaf(wax, bxx, acc[7]);  acc[8]  = fmaf(wax, byy, acc[8]);  acc[9]  = fmaf(wax, bzz, acc[9]);
            acc[10] = fmaf(way, bxx, acc[10]); acc[11] = fmaf(way, byy, acc[11]); acc[12] = fmaf(way, bzz, acc[12]);
            acc[13] = fmaf(waz, bxx, acc[13]); acc[14] = fmaf(waz, byy, acc[14]); acc[15] = fmaf(waz, bzz, acc[15]);
        }
    }

    // per-wave 64-lane butterfly
#pragma unroll
    for (int i = 0; i < 16; ++i) {
        float v = acc[i];
#pragma unroll
        for (int off = 32; off > 0; off >>= 1)
            v += __shfl_down(v, off, 64);
        acc[i] = v;
    }

    // cross-wave combine: 256 B LDS + one barrier
    if (lane == 0) {
#pragma unroll
        for (int i = 0; i < 16; ++i) part[wave][i] = acc[i];
    }
    __syncthreads();
    if (threadIdx.x < 16) {
        const int t = threadIdx.x;
        float s = part[0][t] + part[1][t] + part[2][t] + part[3][t];
        ws[(size_t)b * 16 + t] = s;
    }
}

// Jacobi rotation with COMPILE-TIME indices: every access to Nm/Vv is a
// constant index -> SROA keeps both 4x4 arrays in VGPRs.
template<int P, int Q>
__device__ __forceinline__ void jrot(float (&Nm)[4][4], float (&Vv)[4][4]) {
    const float apq = Nm[P][Q];
    if (fabsf(apq) >= 1e-12f) {
        const float tau = (Nm[Q][Q] - Nm[P][P]) / (2.f * apq);
        const float tt  = copysignf(1.f, tau) / (fabsf(tau) + sqrtf(1.f + tau * tau));
        const float c   = 1.f / sqrtf(1.f + tt * tt);
        const float s   = tt * c;
        const float app = Nm[P][P], aqq = Nm[Q][Q];
        Nm[P][P] = app - tt * apq;
        Nm[Q][Q] = aqq + tt * apq;
        Nm[P][Q] = Nm[Q][P] = 0.f;
#pragma unroll
        for (int k = 0; k < 4; ++k) {
            if (k == P || k == Q) continue;
            const float akp = Nm[k][P], akq = Nm[k][Q];
            Nm[k][P] = Nm[P][k] = c * akp - s * akq;
            Nm[k][Q] = Nm[Q][k] = s * akp + c * akq;
        }
#pragma unroll
        for (int k = 0; k < 4; ++k) {
            const float vkp = Vv[k][P], vkq = Vv[k][Q];
            Vv[k][P] = c * vkp - s * vkq;
            Vv[k][Q] = s * vkp + c * vkq;
        }
    }
}

__global__ __launch_bounds__(64) void wproc_solve(
    const float* __restrict__ ws,
    float* __restrict__ out)
{
    const int b = blockIdx.x * blockDim.x + threadIdx.x;
    if (b >= kB) return;

    float t[16];
#pragma unroll
    for (int i = 0; i < 4; ++i) {
        const float4 v = reinterpret_cast<const float4*>(ws + (size_t)b * 16)[i];
        t[4 * i] = v.x; t[4 * i + 1] = v.y; t[4 * i + 2] = v.z; t[4 * i + 3] = v.w;
    }

    const float W   = t[0];
    const float inv = 1.f / (W + kEps);
    const float S   = W * inv;
    float ca[3], cb[3];
#pragma unroll
    for (int d = 0; d < 3; ++d) { ca[d] = t[1 + d] * inv; cb[d] = t[4 + d] * inv; }

    float M[3][3];
    const float f2 = 2.f - S;
#pragma unroll
    for (int d = 0; d < 3; ++d)
#pragma unroll
        for (int e = 0; e < 3; ++e)
            M[d][e] = t[7 + 3 * d + e] * inv - ca[d] * cb[e] * f2;

    const float T  = M[0][0] + M[1][1] + M[2][2];
    const float cx = M[1][2] - M[2][1];
    const float cy = M[2][0] - M[0][2];
    const float cz = M[0][1] - M[1][0];
    float Nm[4][4];
    Nm[0][0] = T;
    Nm[0][1] = Nm[1][0] = cx;
    Nm[0][2] = Nm[2][0] = cy;
    Nm[0][3] = Nm[3][0] = cz;
    Nm[1][1] = 2.f * M[0][0] - T;
    Nm[2][2] = 2.f * M[1][1] - T;
    Nm[3][3] = 2.f * M[2][2] - T;
    Nm[1][2] = Nm[2][1] = M[0][1] + M[1][0];
    Nm[1][3] = Nm[3][1] = M[0][2] + M[2][0];
    Nm[2][3] = Nm[3][2] = M[1][2] + M[2][1];

    float Vv[4][4] = {{1,0,0,0},{0,1,0,0},{0,0,1,0},{0,0,0,1}};

    for (int sweep = 0; sweep < 6; ++sweep) {
        jrot<0, 1>(Nm, Vv);
        jrot<0, 2>(Nm, Vv);
        jrot<0, 3>(Nm, Vv);
        jrot<1, 2>(Nm, Vv);
        jrot<1, 3>(Nm, Vv);
        jrot<2, 3>(Nm, Vv);
    }

    float best = Nm[0][0];
    float qw = Vv[0][0], qx = Vv[1][0], qy = Vv[2][0], qz = Vv[3][0];
    if (Nm[1][1] > best) { best = Nm[1][1]; qw = Vv[0][1]; qx = Vv[1][1]; qy = Vv[2][1]; qz = Vv[3][1]; }
    if (Nm[2][2] > best) { best = Nm[2][2]; qw = Vv[0][2]; qx = Vv[1][2]; qy = Vv[2][2]; qz = Vv[3][2]; }
    if (Nm[3][3] > best) { best = Nm[3][3]; qw = Vv[0][3]; qx = Vv[1][3]; qy = Vv[2][3]; qz = Vv[3][3]; }

    const float nq = 1.f / sqrtf(qw * qw + qx * qx + qy * qy + qz * qz);
    qw *= nq; qx *= nq; qy *= nq; qz *= nq;

    float R[3][3];
    R[0][0] = 1.f - 2.f * (qy * qy + qz * qz);
    R[0][1] = 2.f * (qx * qy - qw * qz);
    R[0][2] = 2.f * (qx * qz + qw * qy);
    R[1][0] = 2.f * (qx * qy + qw * qz);
    R[1][1] = 1.f - 2.f * (qx * qx + qz * qz);
    R[1][2] = 2.f * (qy * qz - qw * qx);
    R[2][0] = 2.f * (qx * qz - qw * qy);
    R[2][1] = 2.f * (qy * qz + qw * qx);
    R[2][2] = 1.f - 2.f * (qx * qx + qy * qy);

    float* ro = out + (size_t)b * 9;
#pragma unroll
    for (int i = 0; i < 3; ++i)
#pragma unroll
        for (int j = 0; j < 3; ++j)
            ro[3 * i + j] = R[i][j];

    float* to = out + (size_t)kB * 9 + (size_t)b * 3;
#pragma unroll
    for (int i = 0; i < 3; ++i)
        to[i] = cb[i] - (R[i][0] * ca[0] + R[i][1] * ca[1] + R[i][2] * ca[2]);
}

extern "C" void kernel_launch(void* const* d_in, const int* in_sizes, int n_in,
                              void* d_out, int out_size, void* d_ws, size_t ws_size,
                              hipStream_t stream) {
    const float* src      = (const float*)d_in[0];
    const float* src_corr = (const float*)d_in[1];
    const float* weights  = (const float*)d_in[2];
    float* out = (float*)d_out;
    float* ws  = (float*)d_ws;   // 8192*16 floats = 512 KB
    wproc_reduce<<<kB, 64 * kWavesPerBatch, 0, stream>>>(src, src_corr, weights, ws);
    wproc_solve<<<kB / 64, 64, 0, stream>>>(ws, out);
}